// Round 1
// baseline (9472.887 us; speedup 1.0000x reference)
//
#include <hip/hip_runtime.h>
#include <hip/hip_bf16.h>

// ModalityEnhancedLSTM: B=64, S=1024, D=256, H=256.
// out = [hidden_seq (64*1024*256) | h_t (64*256) | c_t (64*256)] f32.
//
// Plan:
//  prep_kernel : shuffle W,U (f32 -> bf16) into MFMA B-fragment layout per
//                "slice" (slice = (colWG m, wave w): 16 gate-cols = 4 j-units
//                x {i,f,g,o}), plus bias into per-slice col layout.
//  xproj_kernel: xp[s,g,slice,lane,4] = x@W + bias (bf16, C-frag layout).
//  lstm_kernel : 32 persistent WGs = 4 batch-groups(16 b) x 8 colWGs(32 j).
//                U slice in registers; h exchanged per step via ws buffer +
//                device-scope flags; c state in registers.

#define S_ 1024
#define BSH 16777216u   // 64*1024*256
#define BH  16384u

typedef short short8 __attribute__((ext_vector_type(8)));
typedef float float4_ __attribute__((ext_vector_type(4)));
typedef unsigned int uint2_ __attribute__((ext_vector_type(2)));
typedef unsigned int uint4_ __attribute__((ext_vector_type(4)));

static __device__ __forceinline__ unsigned short f2bf(float f) {
    unsigned int u = __builtin_bit_cast(unsigned int, f);
    u += 0x7FFFu + ((u >> 16) & 1u);
    return (unsigned short)(u >> 16);
}
static __device__ __forceinline__ float bf2f(unsigned short h) {
    unsigned int u = ((unsigned int)h) << 16;
    return __builtin_bit_cast(float, u);
}
static __device__ __forceinline__ uint4_ pack8(const unsigned short* t) {
    uint4_ v;
    v.x = (unsigned int)t[0] | ((unsigned int)t[1] << 16);
    v.y = (unsigned int)t[2] | ((unsigned int)t[3] << 16);
    v.z = (unsigned int)t[4] | ((unsigned int)t[5] << 16);
    v.w = (unsigned int)t[6] | ((unsigned int)t[7] << 16);
    return v;
}

// ---------------- prep: W,U -> bf16 frag layout; bias -> per-slice ----------
__global__ void prep_kernel(const float* __restrict__ W, const float* __restrict__ U,
                            const float* __restrict__ bias,
                            unsigned short* __restrict__ Wbf, unsigned short* __restrict__ Ubf,
                            float* __restrict__ biasf) {
    int tid = blockIdx.x * blockDim.x + threadIdx.x;
    if (tid < 65536) {
        int idx = tid & 32767;
        const float* src = (tid < 32768) ? W : U;
        unsigned short* dst = (tid < 32768) ? Wbf : Ubf;
        int sl = idx >> 9, kt = (idx >> 6) & 7, lane = idx & 63;
        int c = lane & 15, kgrp = lane >> 4;
        int m = sl >> 3, wv = sl & 7;
        int gate = c >> 2, jj = c & 3;
        int ncol = gate * 256 + 32 * m + 4 * wv + jj;
        unsigned short t8[8];
#pragma unroll
        for (int e = 0; e < 8; e++) {
            int k = kt * 32 + kgrp * 8 + e;
            t8[e] = f2bf(src[k * 1024 + ncol]);
        }
        *(uint4_*)(dst + (size_t)idx * 8) = pack8(t8);
    } else if (tid < 66560) {
        int idx2 = tid - 65536;            // [0,1024)
        int sl = idx2 >> 4, c = idx2 & 15;
        int m = sl >> 3, wv = sl & 7, gate = c >> 2, jj = c & 3;
        int ncol = gate * 256 + 32 * m + 4 * wv + jj;
        biasf[idx2] = bias[ncol];
    }
}

// ---------------- xproj: xp = x @ W + bias, bf16 C-frag layout --------------
__global__ __launch_bounds__(512, 2)
void xproj_kernel(const float* __restrict__ x, const unsigned short* __restrict__ Wbf,
                  const float* __restrict__ biasf, unsigned short* __restrict__ xp) {
    const int bx = blockIdx.x;             // [0,1024)
    const int g = bx & 3, tile = bx >> 2;  // 256 tiles of 4 s each
    const int s0 = tile * 4;
    const int tidx = threadIdx.x;
    const int w = tidx >> 6, lane = tidx & 63;

    __shared__ unsigned short Afrag[4][8][64][8];  // [si][kt][lane][e] 32KB

    {   // stage x (f32 -> bf16 A-frags)
        int row = tidx >> 3;               // 0..63 = si*16 + r
        int kt = tidx & 7;
        int si = row >> 4, r = row & 15;
        int b = g * 16 + r, s = s0 + si;
        const float* px = x + ((size_t)b * 1024 + s) * 256 + kt * 32;
#pragma unroll
        for (int kg = 0; kg < 4; kg++) {
            float4_ v0 = *(const float4_*)(px + kg * 8);
            float4_ v1 = *(const float4_*)(px + kg * 8 + 4);
            unsigned short t8[8] = { f2bf(v0.x), f2bf(v0.y), f2bf(v0.z), f2bf(v0.w),
                                     f2bf(v1.x), f2bf(v1.y), f2bf(v1.z), f2bf(v1.w) };
            *(uint4_*)&Afrag[si][kt][kg * 16 + r][0] = pack8(t8);
        }
    }
    __syncthreads();

    float4_ acc[8][4];
#pragma unroll
    for (int q = 0; q < 8; q++) {
        int sl = w * 8 + q;
        float bv = biasf[sl * 16 + (lane & 15)];
#pragma unroll
        for (int si = 0; si < 4; si++) acc[q][si] = (float4_){bv, bv, bv, bv};
    }
#pragma unroll
    for (int kt = 0; kt < 8; kt++) {
        short8 a[4];
#pragma unroll
        for (int si = 0; si < 4; si++)
            a[si] = *(const short8*)&Afrag[si][kt][lane][0];
#pragma unroll
        for (int q = 0; q < 8; q++) {
            short8 bfr = *(const short8*)(Wbf + (((size_t)(w * 8 + q) * 8 + kt) * 64 + lane) * 8);
#pragma unroll
            for (int si = 0; si < 4; si++)
                acc[q][si] = __builtin_amdgcn_mfma_f32_16x16x32_bf16(a[si], bfr, acc[q][si], 0, 0, 0);
        }
    }
#pragma unroll
    for (int q = 0; q < 8; q++) {
        int sl = w * 8 + q;
#pragma unroll
        for (int si = 0; si < 4; si++) {
            int s = s0 + si;
            unsigned int lo = (unsigned int)f2bf(acc[q][si].x) | ((unsigned int)f2bf(acc[q][si].y) << 16);
            unsigned int hi = (unsigned int)f2bf(acc[q][si].z) | ((unsigned int)f2bf(acc[q][si].w) << 16);
            uint2_ v = {lo, hi};
            *(uint2_*)(xp + (((size_t)(s * 4 + g) * 64 + sl) * 64 + lane) * 4) = v;
        }
    }
}

// ---------------- recurrent scan -------------------------------------------
__global__ __launch_bounds__(512, 2)
void lstm_kernel(const unsigned short* __restrict__ Ubf,
                 const unsigned short* __restrict__ xp,
                 const float* __restrict__ lam,
                 unsigned short* __restrict__ hbuf,
                 unsigned int* __restrict__ flags,
                 float* __restrict__ out) {
    const int bx = blockIdx.x;             // grid 64; use only XCD 0..3 slots
    if ((bx & 7) >= 4) return;
    const int g = bx & 7;                  // batch group 0..3 (one XCD each)
    const int m = bx >> 3;                 // colWG 0..7
    const int tid = threadIdx.x;
    const int w = tid >> 6, lane = tid & 63;
    const int sl = m * 8 + w;

    __shared__ float lamLDS[1024];
    __shared__ unsigned short htmp[2][16][40];  // padded rows
    __shared__ float houtb[2][16][36];

    for (int i = tid; i < 1024; i += 512) lamLDS[i] = lam[i];

    short8 u[8];
#pragma unroll
    for (int kt = 0; kt < 8; kt++)
        u[kt] = *(const short8*)(Ubf + (((size_t)sl * 8 + kt) * 64 + lane) * 8);

    const int col = lane & 15;
    const int gate = col >> 2, jj = col & 3;
    const int r0 = (lane >> 4) * 4;
    const bool active = (gate == 0);

    float cst[4] = {0.f, 0.f, 0.f, 0.f};
    unsigned int* flg = flags + g * 1024;

    size_t xp_idx = ((size_t)(g * 64 + sl) * 64 + lane) * 4;
    const size_t xp_step = (size_t)65536;  // ushorts per t

    uint2_ xpc = *(const uint2_*)(xp + xp_idx);
    __syncthreads();

    for (int t = 0; t < 1024; t++) {
        uint2_ xpn = xpc;
        if (t + 1 < 1024) xpn = *(const uint2_*)(xp + xp_idx + (size_t)(t + 1) * xp_step);

        float4_ acc0, acc1 = (float4_){0.f, 0.f, 0.f, 0.f};
        acc0.x = bf2f((unsigned short)(xpc.x & 0xffff));
        acc0.y = bf2f((unsigned short)(xpc.x >> 16));
        acc0.z = bf2f((unsigned short)(xpc.y & 0xffff));
        acc0.w = bf2f((unsigned short)(xpc.y >> 16));

        if (t > 0) {
            if (lane == 0) {
                while (__hip_atomic_load(&flg[t - 1], __ATOMIC_RELAXED, __HIP_MEMORY_SCOPE_AGENT) < 8u)
                    __builtin_amdgcn_s_sleep(1);
            }
            __builtin_amdgcn_fence(__ATOMIC_ACQUIRE, "agent");
            const unsigned short* hb = hbuf + ((size_t)(t - 1) * 4 + g) * 4096;
            short8 a[8];
#pragma unroll
            for (int kt = 0; kt < 8; kt++)
                a[kt] = *(const short8*)(hb + kt * 512 + lane * 8);
#pragma unroll
            for (int kt = 0; kt < 8; kt += 2) {
                acc0 = __builtin_amdgcn_mfma_f32_16x16x32_bf16(a[kt],     u[kt],     acc0, 0, 0, 0);
                acc1 = __builtin_amdgcn_mfma_f32_16x16x32_bf16(a[kt + 1], u[kt + 1], acc1, 0, 0, 0);
            }
        }

        float lamt = lamLDS[t];
        float gv[4], fv[4], ggv[4], ov[4];
#pragma unroll
        for (int q = 0; q < 4; q++) {
            float xg = acc0[q] + acc1[q];
            float y = (gate == 2) ? 2.f * xg : xg;
            float sgm = 1.f / (1.f + __expf(-y));
            gv[q] = (gate == 2) ? 2.f * sgm - 1.f : sgm;
        }
#pragma unroll
        for (int q = 0; q < 4; q++) {
            fv[q]  = __shfl(gv[q], lane + 4, 64);
            ggv[q] = __shfl(gv[q], lane + 8, 64);
            ov[q]  = __shfl(gv[q], lane + 12, 64);
        }

        const int buf = t & 1;
        if (active) {
            float hq[4];
#pragma unroll
            for (int q = 0; q < 4; q++) {
                float c = fv[q] * cst[q] + gv[q] * ggv[q] * lamt;
                cst[q] = c;
                float th = 2.f / (1.f + __expf(-2.f * c)) - 1.f;
                hq[q] = ov[q] * th;
            }
#pragma unroll
            for (int q = 0; q < 4; q++) {
                htmp[buf][r0 + q][4 * w + jj] = f2bf(hq[q]);
                houtb[buf][r0 + q][4 * w + jj] = hq[q];
            }
            if (t == 1023) {
#pragma unroll
                for (int q = 0; q < 4; q++) {
                    size_t b = (size_t)g * 16 + r0 + q;
                    int j = m * 32 + 4 * w + jj;
                    out[BSH + b * 256 + j] = hq[q];
                    out[BSH + BH + b * 256 + j] = cst[q];
                }
            }
        }
        __syncthreads();

        if (w == 0) {
            int r = lane & 15, kg = lane >> 4;
            uint4_ v = *(const uint4_*)&htmp[buf][r][kg * 8];
            unsigned short* dst = hbuf + ((size_t)t * 4 + g) * 4096 + m * 512 + lane * 8;
            *(uint4_*)dst = v;
            __builtin_amdgcn_fence(__ATOMIC_RELEASE, "agent");
            if (lane == 0)
                __hip_atomic_fetch_add(&flg[t], 1u, __ATOMIC_RELAXED, __HIP_MEMORY_SCOPE_AGENT);
        } else if (w == 1) {
            int r = lane >> 2, seg = lane & 3;
            float4_ v0 = *(const float4_*)&houtb[buf][r][seg * 8];
            float4_ v1 = *(const float4_*)&houtb[buf][r][seg * 8 + 4];
            float* po = out + (((size_t)(g * 16 + r)) << 18) + ((size_t)t << 8) + m * 32 + seg * 8;
            *(float4_*)po = v0;
            *(float4_*)(po + 4) = v1;
        }
        xpc = xpn;
    }
}

__global__ void ws_too_small_kernel(float* out) {
    if (threadIdx.x == 0 && blockIdx.x == 0) out[0] = -777777.0f;
}

extern "C" void kernel_launch(void* const* d_in, const int* in_sizes, int n_in,
                              void* d_out, int out_size, void* d_ws, size_t ws_size,
                              hipStream_t stream) {
    const float* x    = (const float*)d_in[0];
    const float* lam  = (const float*)d_in[1];
    const float* W    = (const float*)d_in[2];
    const float* U    = (const float*)d_in[3];
    const float* bias = (const float*)d_in[4];
    float* out = (float*)d_out;

    const size_t NEED = (size_t)162 << 20;   // 2MiB prep + 32MiB hbuf + 128MiB xp
    if (ws_size < NEED) {
        ws_too_small_kernel<<<1, 64, 0, stream>>>(out);
        return;
    }
    char* ws = (char*)d_ws;
    unsigned int*   flags = (unsigned int*)(ws);                       // 16KB used
    unsigned short* Ubf   = (unsigned short*)(ws + (64 << 10));        // 512KB
    unsigned short* Wbf   = (unsigned short*)(ws + (576 << 10));       // 512KB
    float*          biasf = (float*)(ws + (1088 << 10));               // 4KB
    unsigned short* hbuf  = (unsigned short*)(ws + ((size_t)2 << 20)); // 32MiB
    unsigned short* xp    = (unsigned short*)(ws + ((size_t)34 << 20));// 128MiB

    hipMemsetAsync(flags, 0, 4 * 1024 * sizeof(unsigned int), stream);
    prep_kernel<<<260, 256, 0, stream>>>(W, U, bias, Wbf, Ubf, biasf);
    xproj_kernel<<<1024, 512, 0, stream>>>(x, Wbf, biasf, xp);
    lstm_kernel<<<64, 512, 0, stream>>>(Ubf, xp, lam, hbuf, flags, out);
}

// Round 2
// 3417.068 us; speedup vs baseline: 2.7722x; 2.7722x over previous
//
#include <hip/hip_runtime.h>
#include <hip/hip_bf16.h>

// ModalityEnhancedLSTM: B=64, S=1024, D=256, H=256.
// out = [hidden_seq (64*1024*256) | h_t (64*256) | c_t (64*256)] f32.
//
//  prep_kernel : W,U f32 -> bf16 MFMA B-frag layout; bias -> per-slice cols.
//  xproj_kernel: xp = x@W + bias, bf16 C-frag layout, per (s, group, slice).
//  lstm_kernel : 32 persistent WGs = 4 batch-groups(16 b) x 8 colWGs(32 j).
//                U slice in registers; h exchanged per step via L3-coherent
//                relaxed agent atomics + per-writer flags (NO acquire/release
//                fences -> no per-step buffer_wbl2/buffer_inv L2 maintenance).

#define S_ 1024
#define BSH 16777216u   // 64*1024*256
#define BH  16384u

typedef short short8 __attribute__((ext_vector_type(8)));
typedef float float4_ __attribute__((ext_vector_type(4)));
typedef unsigned int uint2_ __attribute__((ext_vector_type(2)));
typedef unsigned int uint4_ __attribute__((ext_vector_type(4)));

static __device__ __forceinline__ unsigned short f2bf(float f) {
    unsigned int u = __builtin_bit_cast(unsigned int, f);
    u += 0x7FFFu + ((u >> 16) & 1u);
    return (unsigned short)(u >> 16);
}
static __device__ __forceinline__ float bf2f(unsigned short h) {
    unsigned int u = ((unsigned int)h) << 16;
    return __builtin_bit_cast(float, u);
}
static __device__ __forceinline__ uint4_ pack8(const unsigned short* t) {
    uint4_ v;
    v.x = (unsigned int)t[0] | ((unsigned int)t[1] << 16);
    v.y = (unsigned int)t[2] | ((unsigned int)t[3] << 16);
    v.z = (unsigned int)t[4] | ((unsigned int)t[5] << 16);
    v.w = (unsigned int)t[6] | ((unsigned int)t[7] << 16);
    return v;
}

// ---------------- prep: W,U -> bf16 frag layout; bias -> per-slice ----------
__global__ void prep_kernel(const float* __restrict__ W, const float* __restrict__ U,
                            const float* __restrict__ bias,
                            unsigned short* __restrict__ Wbf, unsigned short* __restrict__ Ubf,
                            float* __restrict__ biasf) {
    int tid = blockIdx.x * blockDim.x + threadIdx.x;
    if (tid < 65536) {
        int idx = tid & 32767;
        const float* src = (tid < 32768) ? W : U;
        unsigned short* dst = (tid < 32768) ? Wbf : Ubf;
        int sl = idx >> 9, kt = (idx >> 6) & 7, lane = idx & 63;
        int c = lane & 15, kgrp = lane >> 4;
        int m = sl >> 3, wv = sl & 7;
        int gate = c >> 2, jj = c & 3;
        int ncol = gate * 256 + 32 * m + 4 * wv + jj;
        unsigned short t8[8];
#pragma unroll
        for (int e = 0; e < 8; e++) {
            int k = kt * 32 + kgrp * 8 + e;
            t8[e] = f2bf(src[k * 1024 + ncol]);
        }
        *(uint4_*)(dst + (size_t)idx * 8) = pack8(t8);
    } else if (tid < 66560) {
        int idx2 = tid - 65536;            // [0,1024)
        int sl = idx2 >> 4, c = idx2 & 15;
        int m = sl >> 3, wv = sl & 7, gate = c >> 2, jj = c & 3;
        int ncol = gate * 256 + 32 * m + 4 * wv + jj;
        biasf[idx2] = bias[ncol];
    }
}

// ---------------- xproj: xp = x @ W + bias, bf16 C-frag layout --------------
__global__ __launch_bounds__(512, 2)
void xproj_kernel(const float* __restrict__ x, const unsigned short* __restrict__ Wbf,
                  const float* __restrict__ biasf, unsigned short* __restrict__ xp) {
    const int bx = blockIdx.x;             // [0,1024)
    const int g = bx & 3, tile = bx >> 2;  // 256 tiles of 4 s each
    const int s0 = tile * 4;
    const int tidx = threadIdx.x;
    const int w = tidx >> 6, lane = tidx & 63;

    __shared__ unsigned short Afrag[4][8][64][8];  // [si][kt][lane][e] 32KB

    {   // stage x (f32 -> bf16 A-frags)
        int row = tidx >> 3;               // 0..63 = si*16 + r
        int kt = tidx & 7;
        int si = row >> 4, r = row & 15;
        int b = g * 16 + r, s = s0 + si;
        const float* px = x + ((size_t)b * 1024 + s) * 256 + kt * 32;
#pragma unroll
        for (int kg = 0; kg < 4; kg++) {
            float4_ v0 = *(const float4_*)(px + kg * 8);
            float4_ v1 = *(const float4_*)(px + kg * 8 + 4);
            unsigned short t8[8] = { f2bf(v0.x), f2bf(v0.y), f2bf(v0.z), f2bf(v0.w),
                                     f2bf(v1.x), f2bf(v1.y), f2bf(v1.z), f2bf(v1.w) };
            *(uint4_*)&Afrag[si][kt][kg * 16 + r][0] = pack8(t8);
        }
    }
    __syncthreads();

    float4_ acc[8][4];
#pragma unroll
    for (int q = 0; q < 8; q++) {
        int sl = w * 8 + q;
        float bv = biasf[sl * 16 + (lane & 15)];
#pragma unroll
        for (int si = 0; si < 4; si++) acc[q][si] = (float4_){bv, bv, bv, bv};
    }
#pragma unroll
    for (int kt = 0; kt < 8; kt++) {
        short8 a[4];
#pragma unroll
        for (int si = 0; si < 4; si++)
            a[si] = *(const short8*)&Afrag[si][kt][lane][0];
#pragma unroll
        for (int q = 0; q < 8; q++) {
            short8 bfr = *(const short8*)(Wbf + (((size_t)(w * 8 + q) * 8 + kt) * 64 + lane) * 8);
#pragma unroll
            for (int si = 0; si < 4; si++)
                acc[q][si] = __builtin_amdgcn_mfma_f32_16x16x32_bf16(a[si], bfr, acc[q][si], 0, 0, 0);
        }
    }
#pragma unroll
    for (int q = 0; q < 8; q++) {
        int sl = w * 8 + q;
#pragma unroll
        for (int si = 0; si < 4; si++) {
            int s = s0 + si;
            unsigned int lo = (unsigned int)f2bf(acc[q][si].x) | ((unsigned int)f2bf(acc[q][si].y) << 16);
            unsigned int hi = (unsigned int)f2bf(acc[q][si].z) | ((unsigned int)f2bf(acc[q][si].w) << 16);
            uint2_ v = {lo, hi};
            *(uint2_*)(xp + (((size_t)(s * 4 + g) * 64 + sl) * 64 + lane) * 4) = v;
        }
    }
}

// ---------------- recurrent scan -------------------------------------------
union U64x2 { unsigned long long u[2]; short8 s; };

__global__ __launch_bounds__(512, 2)
void lstm_kernel(const unsigned short* __restrict__ Ubf,
                 const unsigned short* __restrict__ xp,
                 const float* __restrict__ lam,
                 unsigned short* __restrict__ hbuf,
                 unsigned int* __restrict__ flags,
                 float* __restrict__ out) {
    const int bx = blockIdx.x;             // grid 32
    const int g = bx & 3;                  // batch group 0..3
    const int m = bx >> 2;                 // colWG 0..7
    const int tid = threadIdx.x;
    const int w = tid >> 6, lane = tid & 63;
    const int sl = m * 8 + w;

    __shared__ float lamLDS[1024];
    __shared__ unsigned short htmp[2][16][40];  // padded rows
    __shared__ float houtb[2][16][36];

    for (int i = tid; i < 1024; i += 512) lamLDS[i] = lam[i];

    short8 u[8];
#pragma unroll
    for (int kt = 0; kt < 8; kt++)
        u[kt] = *(const short8*)(Ubf + (((size_t)sl * 8 + kt) * 64 + lane) * 8);

    const int col = lane & 15;
    const int gate = col >> 2, jj = col & 3;
    const int r0 = (lane >> 4) * 4;
    const bool active = (gate == 0);

    float cst[4] = {0.f, 0.f, 0.f, 0.f};
    unsigned int* flg = flags + g * 8192;       // [t][writer m]

    size_t xp_idx = ((size_t)(g * 64 + sl) * 64 + lane) * 4;
    const size_t xp_step = (size_t)65536;  // ushorts per t

    uint2_ xpc = *(const uint2_*)(xp + xp_idx);
    __syncthreads();

    for (int t = 0; t < 1024; t++) {
        uint2_ xpn = xpc;
        if (t + 1 < 1024) xpn = *(const uint2_*)(xp + xp_idx + (size_t)(t + 1) * xp_step);

        float4_ acc0, acc1 = (float4_){0.f, 0.f, 0.f, 0.f};
        acc0.x = bf2f((unsigned short)(xpc.x & 0xffff));
        acc0.y = bf2f((unsigned short)(xpc.x >> 16));
        acc0.z = bf2f((unsigned short)(xpc.y & 0xffff));
        acc0.w = bf2f((unsigned short)(xpc.y >> 16));

        if (t > 0) {
            // wait for all 8 writers of step t-1 (per-writer flags, no fence)
            const unsigned int* fl = flg + (size_t)(t - 1) * 8;
            unsigned int v = (lane < 8) ? 0u : 1u;
            while (true) {
                if (lane < 8 && v == 0)
                    v = __hip_atomic_load(&fl[lane], __ATOMIC_RELAXED, __HIP_MEMORY_SCOPE_AGENT);
                if (__all(v != 0)) break;
            }
            asm volatile("" ::: "memory");

            const unsigned short* hb = hbuf + ((size_t)(t - 1) * 4 + g) * 4096;
            unsigned long long raw[16];
#pragma unroll
            for (int kt = 0; kt < 8; kt++) {
                const unsigned long long* p =
                    (const unsigned long long*)(hb + kt * 512 + lane * 8);
                raw[2 * kt]     = __hip_atomic_load(p,     __ATOMIC_RELAXED, __HIP_MEMORY_SCOPE_AGENT);
                raw[2 * kt + 1] = __hip_atomic_load(p + 1, __ATOMIC_RELAXED, __HIP_MEMORY_SCOPE_AGENT);
            }
            short8 a[8];
#pragma unroll
            for (int kt = 0; kt < 8; kt++) {
                U64x2 cvt;
                cvt.u[0] = raw[2 * kt];
                cvt.u[1] = raw[2 * kt + 1];
                a[kt] = cvt.s;
            }
#pragma unroll
            for (int kt = 0; kt < 8; kt += 2) {
                acc0 = __builtin_amdgcn_mfma_f32_16x16x32_bf16(a[kt],     u[kt],     acc0, 0, 0, 0);
                acc1 = __builtin_amdgcn_mfma_f32_16x16x32_bf16(a[kt + 1], u[kt + 1], acc1, 0, 0, 0);
            }
        }

        float lamt = lamLDS[t];
        float gv[4], fv[4], ggv[4], ov[4];
#pragma unroll
        for (int q = 0; q < 4; q++) {
            float xg = acc0[q] + acc1[q];
            float y = (gate == 2) ? 2.f * xg : xg;
            float sgm = 1.f / (1.f + __expf(-y));
            gv[q] = (gate == 2) ? 2.f * sgm - 1.f : sgm;
        }
#pragma unroll
        for (int q = 0; q < 4; q++) {
            fv[q]  = __shfl(gv[q], lane + 4, 64);
            ggv[q] = __shfl(gv[q], lane + 8, 64);
            ov[q]  = __shfl(gv[q], lane + 12, 64);
        }

        const int buf = t & 1;
        if (active) {
            float hq[4];
#pragma unroll
            for (int q = 0; q < 4; q++) {
                float c = fv[q] * cst[q] + gv[q] * ggv[q] * lamt;
                cst[q] = c;
                float th = 2.f / (1.f + __expf(-2.f * c)) - 1.f;
                hq[q] = ov[q] * th;
            }
#pragma unroll
            for (int q = 0; q < 4; q++) {
                htmp[buf][r0 + q][4 * w + jj] = f2bf(hq[q]);
                houtb[buf][r0 + q][4 * w + jj] = hq[q];
            }
            if (t == 1023) {
#pragma unroll
                for (int q = 0; q < 4; q++) {
                    size_t b = (size_t)g * 16 + r0 + q;
                    int j = m * 32 + 4 * w + jj;
                    out[BSH + b * 256 + j] = hq[q];
                    out[BSH + BH + b * 256 + j] = cst[q];
                }
            }
        }
        __syncthreads();

        if (w == 0) {
            int r = lane & 15, kg = lane >> 4;
            uint4_ v = *(const uint4_*)&htmp[buf][r][kg * 8];
            unsigned long long lo = ((unsigned long long)v.y << 32) | (unsigned long long)v.x;
            unsigned long long hi = ((unsigned long long)v.w << 32) | (unsigned long long)v.z;
            unsigned long long* dst =
                (unsigned long long*)(hbuf + ((size_t)t * 4 + g) * 4096 + m * 512 + lane * 8);
            __hip_atomic_store(dst,     lo, __ATOMIC_RELAXED, __HIP_MEMORY_SCOPE_AGENT);
            __hip_atomic_store(dst + 1, hi, __ATOMIC_RELAXED, __HIP_MEMORY_SCOPE_AGENT);
            asm volatile("s_waitcnt vmcnt(0)" ::: "memory");
            if (lane == 0)
                __hip_atomic_store(&flg[(size_t)t * 8 + m], 1u,
                                   __ATOMIC_RELAXED, __HIP_MEMORY_SCOPE_AGENT);
        } else if (w == 1) {
            int r = lane >> 2, seg = lane & 3;
            float4_ v0 = *(const float4_*)&houtb[buf][r][seg * 8];
            float4_ v1 = *(const float4_*)&houtb[buf][r][seg * 8 + 4];
            float* po = out + (((size_t)(g * 16 + r)) << 18) + ((size_t)t << 8) + m * 32 + seg * 8;
            *(float4_*)po = v0;
            *(float4_*)(po + 4) = v1;
        }
        xpc = xpn;
    }
}

__global__ void ws_too_small_kernel(float* out) {
    if (threadIdx.x == 0 && blockIdx.x == 0) out[0] = -777777.0f;
}

extern "C" void kernel_launch(void* const* d_in, const int* in_sizes, int n_in,
                              void* d_out, int out_size, void* d_ws, size_t ws_size,
                              hipStream_t stream) {
    const float* x    = (const float*)d_in[0];
    const float* lam  = (const float*)d_in[1];
    const float* W    = (const float*)d_in[2];
    const float* U    = (const float*)d_in[3];
    const float* bias = (const float*)d_in[4];
    float* out = (float*)d_out;

    const size_t NEED = (size_t)162 << 20;   // 2MiB prep/flags + 32MiB hbuf + 128MiB xp
    if (ws_size < NEED) {
        ws_too_small_kernel<<<1, 64, 0, stream>>>(out);
        return;
    }
    char* ws = (char*)d_ws;
    unsigned int*   flags = (unsigned int*)(ws);                       // 128KB (4*1024*8*4B)
    unsigned short* Ubf   = (unsigned short*)(ws + (256 << 10));       // 512KB
    unsigned short* Wbf   = (unsigned short*)(ws + (768 << 10));       // 512KB
    float*          biasf = (float*)(ws + (1280 << 10));               // 4KB
    unsigned short* hbuf  = (unsigned short*)(ws + ((size_t)2 << 20)); // 32MiB
    unsigned short* xp    = (unsigned short*)(ws + ((size_t)34 << 20));// 128MiB

    hipMemsetAsync(flags, 0, 4 * 1024 * 8 * sizeof(unsigned int), stream);
    prep_kernel<<<260, 256, 0, stream>>>(W, U, bias, Wbf, Ubf, biasf);
    xproj_kernel<<<1024, 512, 0, stream>>>(x, Wbf, biasf, xp);
    lstm_kernel<<<32, 512, 0, stream>>>(Ubf, xp, lam, hbuf, flags, out);
}

// Round 3
// 2225.742 us; speedup vs baseline: 4.2561x; 1.5352x over previous
//
#include <hip/hip_runtime.h>
#include <hip/hip_bf16.h>

// ModalityEnhancedLSTM: B=64, S=1024, D=256, H=256.
// out = [hidden_seq (64*1024*256) | h_t (64*256) | c_t (64*256)] f32.
//
//  prep_kernel : W -> bf16 B-frag layout; U -> NEGATED bf16 B-frag layout
//                (so MFMA((-h),(-U)) == h@U and writers can store -h, whose
//                bf16 pattern is provably nonzero -> data-is-the-flag poll).
//  xproj_kernel: xp = x@W + bias, bf16, [wg][t][slice][lane][4] layout.
//  lstm_kernel : 32 persistent WGs = 4 batch-groups(16 b) x 8 colWGs(32 j),
//                9 waves each: w0-7 compute (U slice in regs, poll h directly
//                from L3 with sc0 sc1 loads), w8 service (xp global_load_lds
//                ring with counted vmcnt + hidden_seq stores). Raw s_barrier
//                (lgkmcnt only) so no per-step vmcnt(0) drain.

#define BSH 16777216u   // 64*1024*256
#define BH  16384u

typedef short short8 __attribute__((ext_vector_type(8)));
typedef float float4_ __attribute__((ext_vector_type(4)));
typedef unsigned int uint2_ __attribute__((ext_vector_type(2)));
typedef unsigned int uint4_ __attribute__((ext_vector_type(4)));

static __device__ __forceinline__ unsigned short f2bf(float f) {
    unsigned int u = __builtin_bit_cast(unsigned int, f);
    u += 0x7FFFu + ((u >> 16) & 1u);
    return (unsigned short)(u >> 16);
}
static __device__ __forceinline__ float bf2f(unsigned short h) {
    unsigned int u = ((unsigned int)h) << 16;
    return __builtin_bit_cast(float, u);
}
static __device__ __forceinline__ uint4_ pack8(const unsigned short* t) {
    uint4_ v;
    v.x = (unsigned int)t[0] | ((unsigned int)t[1] << 16);
    v.y = (unsigned int)t[2] | ((unsigned int)t[3] << 16);
    v.z = (unsigned int)t[4] | ((unsigned int)t[5] << 16);
    v.w = (unsigned int)t[6] | ((unsigned int)t[7] << 16);
    return v;
}
static __device__ __forceinline__ unsigned umin_(unsigned a, unsigned b) {
    return a < b ? a : b;
}
static __device__ __forceinline__ void gload_lds16(const void* g, void* l) {
    __builtin_amdgcn_global_load_lds(
        (const __attribute__((address_space(1))) unsigned int*)g,
        (__attribute__((address_space(3))) unsigned int*)l, 16, 0, 0);
}
static __device__ __forceinline__ void barrier_lgkm() {
    asm volatile("s_waitcnt lgkmcnt(0)" ::: "memory");
    __builtin_amdgcn_s_barrier();
    asm volatile("" ::: "memory");
}

// ---------------- prep: W,(-U) -> bf16 frag layout; bias -> per-slice -------
__global__ void prep_kernel(const float* __restrict__ W, const float* __restrict__ U,
                            const float* __restrict__ bias,
                            unsigned short* __restrict__ Wbf, unsigned short* __restrict__ Ubf,
                            float* __restrict__ biasf) {
    int tid = blockIdx.x * blockDim.x + threadIdx.x;
    if (tid < 65536) {
        int idx = tid & 32767;
        const bool isU = (tid >= 32768);
        const float* src = isU ? U : W;
        unsigned short* dst = isU ? Ubf : Wbf;
        int sl = idx >> 9, kt = (idx >> 6) & 7, lane = idx & 63;
        int c = lane & 15, kgrp = lane >> 4;
        int m = sl >> 3, wv = sl & 7;
        int gatec = c >> 2, jj = c & 3;
        int ncol = gatec * 256 + 32 * m + 4 * wv + jj;
        unsigned short t8[8];
#pragma unroll
        for (int e = 0; e < 8; e++) {
            int k = kt * 32 + kgrp * 8 + e;
            float v = src[k * 1024 + ncol];
            t8[e] = f2bf(isU ? -v : v);
        }
        *(uint4_*)(dst + (size_t)idx * 8) = pack8(t8);
    } else if (tid < 66560) {
        int idx2 = tid - 65536;            // [0,1024)
        int sl = idx2 >> 4, c = idx2 & 15;
        int m = sl >> 3, wv = sl & 7, gatec = c >> 2, jj = c & 3;
        int ncol = gatec * 256 + 32 * m + 4 * wv + jj;
        biasf[idx2] = bias[ncol];
    }
}

// ---------------- xproj: xp = x @ W + bias, bf16, per-WG layout -------------
__global__ __launch_bounds__(512, 2)
void xproj_kernel(const float* __restrict__ x, const unsigned short* __restrict__ Wbf,
                  const float* __restrict__ biasf, unsigned short* __restrict__ xp) {
    const int bx = blockIdx.x;             // [0,1024)
    const int g = bx & 3, tile = bx >> 2;  // 256 tiles of 4 s each
    const int s0 = tile * 4;
    const int tidx = threadIdx.x;
    const int w = tidx >> 6, lane = tidx & 63;

    __shared__ unsigned short Afrag[4][8][64][8];  // [si][kt][lane][e] 32KB

    {   // stage x (f32 -> bf16 A-frags)
        int row = tidx >> 3;               // 0..63 = si*16 + r
        int kt = tidx & 7;
        int si = row >> 4, r = row & 15;
        int b = g * 16 + r, s = s0 + si;
        const float* px = x + ((size_t)b * 1024 + s) * 256 + kt * 32;
#pragma unroll
        for (int kg = 0; kg < 4; kg++) {
            float4_ v0 = *(const float4_*)(px + kg * 8);
            float4_ v1 = *(const float4_*)(px + kg * 8 + 4);
            unsigned short t8[8] = { f2bf(v0.x), f2bf(v0.y), f2bf(v0.z), f2bf(v0.w),
                                     f2bf(v1.x), f2bf(v1.y), f2bf(v1.z), f2bf(v1.w) };
            *(uint4_*)&Afrag[si][kt][kg * 16 + r][0] = pack8(t8);
        }
    }
    __syncthreads();

    float4_ acc[8][4];
#pragma unroll
    for (int q = 0; q < 8; q++) {
        int sl = w * 8 + q;
        float bv = biasf[sl * 16 + (lane & 15)];
#pragma unroll
        for (int si = 0; si < 4; si++) acc[q][si] = (float4_){bv, bv, bv, bv};
    }
#pragma unroll
    for (int kt = 0; kt < 8; kt++) {
        short8 a[4];
#pragma unroll
        for (int si = 0; si < 4; si++)
            a[si] = *(const short8*)&Afrag[si][kt][lane][0];
#pragma unroll
        for (int q = 0; q < 8; q++) {
            short8 bfr = *(const short8*)(Wbf + (((size_t)(w * 8 + q) * 8 + kt) * 64 + lane) * 8);
#pragma unroll
            for (int si = 0; si < 4; si++)
                acc[q][si] = __builtin_amdgcn_mfma_f32_16x16x32_bf16(a[si], bfr, acc[q][si], 0, 0, 0);
        }
    }
#pragma unroll
    for (int q = 0; q < 8; q++) {
        int sl = w * 8 + q;
        int wgx = g * 8 + (sl >> 3);
#pragma unroll
        for (int si = 0; si < 4; si++) {
            int s = s0 + si;
            unsigned int lo = (unsigned int)f2bf(acc[q][si].x) | ((unsigned int)f2bf(acc[q][si].y) << 16);
            unsigned int hi = (unsigned int)f2bf(acc[q][si].z) | ((unsigned int)f2bf(acc[q][si].w) << 16);
            uint2_ v = {lo, hi};
            *(uint2_*)(xp + ((((size_t)wgx * 1024 + s) * 8 + (sl & 7)) * 64 + lane) * 4) = v;
        }
    }
}

// ---------------- recurrent scan -------------------------------------------
__global__ __launch_bounds__(576, 1)
void lstm_kernel(const unsigned short* __restrict__ Ubf,
                 const unsigned short* __restrict__ xp,
                 const float* __restrict__ lam,
                 unsigned short* __restrict__ hbuf,   // zero-initialized
                 float* __restrict__ out) {
    const int bx = blockIdx.x;             // grid 32
    const int g = bx & 3;                  // batch group 0..3
    const int m = bx >> 2;                 // colWG 0..7
    const int tid = threadIdx.x;
    const int w = tid >> 6, lane = tid & 63;

    __shared__ float lamLDS[1024];
    __shared__ unsigned short htmp[2][16][40];   // -h, bf16, padded rows
    __shared__ unsigned short xpring[8][2048];   // [slot][slice*256 + lane*4]

    for (int i = tid; i < 1024; i += 576) lamLDS[i] = lam[i];

    const int col = lane & 15;
    const int gatec = col >> 2, jj = col & 3;
    const int rr0 = (lane >> 4) * 4;
    const bool active = (gatec == 0);

    short8 u[8];
    if (w < 8) {
        int sl = m * 8 + w;
#pragma unroll
        for (int kt = 0; kt < 8; kt++)
            u[kt] = *(const short8*)(Ubf + (((size_t)sl * 8 + kt) * 64 + lane) * 8);
    }

    const size_t wgx = (size_t)(g * 8 + m);

    if (w == 8) {   // prologue: prefetch xp steps 0..5
        for (int s = 0; s < 6; s++) {
            const char* src = (const char*)xp + ((wgx * 1024 + s) << 12) + (size_t)lane * 16;
            char* dst = (char*)&xpring[s][0];
#pragma unroll
            for (int c2 = 0; c2 < 4; c2++)
                gload_lds16(src + c2 * 1024, dst + c2 * 1024);
        }
        asm volatile("s_waitcnt vmcnt(20)" ::: "memory");   // slot 0 ready
    }
    float cst[4] = {0.f, 0.f, 0.f, 0.f};
    barrier_lgkm();

    for (int t = 0; t < 1024; t++) {
        if (w < 8) {
            unsigned long long xpd =
                *(const unsigned long long*)&xpring[t & 7][w * 256 + lane * 4];
            float4_ acc0, acc1 = (float4_){0.f, 0.f, 0.f, 0.f};
            acc0.x = bf2f((unsigned short)(xpd & 0xffff));
            acc0.y = bf2f((unsigned short)((xpd >> 16) & 0xffff));
            acc0.z = bf2f((unsigned short)((xpd >> 32) & 0xffff));
            acc0.w = bf2f((unsigned short)(xpd >> 48));

            if (t > 0) {
                const char* pb = (const char*)hbuf +
                                 (((size_t)(t - 1) * 4 + g) << 13) + (size_t)lane * 16;
                {   // phase-1 light poll: this wave watches block kt==w
                    uint4_ r;
                    const char* pw = pb + w * 1024;
                    for (;;) {
                        asm volatile("global_load_dwordx4 %0, %1, off sc0 sc1\n\t"
                                     "s_waitcnt vmcnt(0)"
                                     : "=v"(r) : "v"(pw) : "memory");
                        __builtin_amdgcn_sched_barrier(0);
                        unsigned mn = umin_(umin_(r.x, r.y), umin_(r.z, r.w));
                        if (__all(mn != 0u)) break;
                    }
                }
                uint4_ r0, r1, r2, r3, r4, r5, r6, r7;
                const char* pbl = pb;
                const char* pbh = pb + 4096;
                for (;;) {   // phase-2: fetch+verify all 8 blocks
                    asm volatile(
                        "global_load_dwordx4 %0, %8, off sc0 sc1\n\t"
                        "global_load_dwordx4 %1, %8, off offset:1024 sc0 sc1\n\t"
                        "global_load_dwordx4 %2, %8, off offset:2048 sc0 sc1\n\t"
                        "global_load_dwordx4 %3, %8, off offset:3072 sc0 sc1\n\t"
                        "global_load_dwordx4 %4, %9, off sc0 sc1\n\t"
                        "global_load_dwordx4 %5, %9, off offset:1024 sc0 sc1\n\t"
                        "global_load_dwordx4 %6, %9, off offset:2048 sc0 sc1\n\t"
                        "global_load_dwordx4 %7, %9, off offset:3072 sc0 sc1\n\t"
                        "s_waitcnt vmcnt(0)"
                        : "=v"(r0), "=v"(r1), "=v"(r2), "=v"(r3),
                          "=v"(r4), "=v"(r5), "=v"(r6), "=v"(r7)
                        : "v"(pbl), "v"(pbh) : "memory");
                    __builtin_amdgcn_sched_barrier(0);
                    unsigned mn = umin_(
                        umin_(umin_(umin_(r0.x, r0.y), umin_(r0.z, r0.w)),
                              umin_(umin_(r1.x, r1.y), umin_(r1.z, r1.w))),
                        umin_(umin_(umin_(r2.x, r2.y), umin_(r2.z, r2.w)),
                              umin_(umin_(r3.x, r3.y), umin_(r3.z, r3.w))));
                    unsigned mn2 = umin_(
                        umin_(umin_(umin_(r4.x, r4.y), umin_(r4.z, r4.w)),
                              umin_(umin_(r5.x, r5.y), umin_(r5.z, r5.w))),
                        umin_(umin_(umin_(r6.x, r6.y), umin_(r6.z, r6.w)),
                              umin_(umin_(r7.x, r7.y), umin_(r7.z, r7.w))));
                    if (__all(umin_(mn, mn2) != 0u)) break;
                }
                acc0 = __builtin_amdgcn_mfma_f32_16x16x32_bf16(__builtin_bit_cast(short8, r0), u[0], acc0, 0, 0, 0);
                acc1 = __builtin_amdgcn_mfma_f32_16x16x32_bf16(__builtin_bit_cast(short8, r1), u[1], acc1, 0, 0, 0);
                acc0 = __builtin_amdgcn_mfma_f32_16x16x32_bf16(__builtin_bit_cast(short8, r2), u[2], acc0, 0, 0, 0);
                acc1 = __builtin_amdgcn_mfma_f32_16x16x32_bf16(__builtin_bit_cast(short8, r3), u[3], acc1, 0, 0, 0);
                acc0 = __builtin_amdgcn_mfma_f32_16x16x32_bf16(__builtin_bit_cast(short8, r4), u[4], acc0, 0, 0, 0);
                acc1 = __builtin_amdgcn_mfma_f32_16x16x32_bf16(__builtin_bit_cast(short8, r5), u[5], acc1, 0, 0, 0);
                acc0 = __builtin_amdgcn_mfma_f32_16x16x32_bf16(__builtin_bit_cast(short8, r6), u[6], acc0, 0, 0, 0);
                acc1 = __builtin_amdgcn_mfma_f32_16x16x32_bf16(__builtin_bit_cast(short8, r7), u[7], acc1, 0, 0, 0);
            }

            float lamt = lamLDS[t];
            float gv[4], fv[4], ggv[4], ov[4];
#pragma unroll
            for (int q = 0; q < 4; q++) {
                float xg = acc0[q] + acc1[q];
                float y = (gatec == 2) ? 2.f * xg : xg;
                float sgm = 1.f / (1.f + __expf(-y));
                gv[q] = (gatec == 2) ? 2.f * sgm - 1.f : sgm;
            }
#pragma unroll
            for (int q = 0; q < 4; q++) {
                fv[q]  = __shfl(gv[q], lane + 4, 64);
                ggv[q] = __shfl(gv[q], lane + 8, 64);
                ov[q]  = __shfl(gv[q], lane + 12, 64);
            }
            if (active) {
                float hq[4];
#pragma unroll
                for (int q = 0; q < 4; q++) {
                    float c = fv[q] * cst[q] + gv[q] * ggv[q] * lamt;
                    cst[q] = c;
                    float th = 2.f / (1.f + __expf(-2.f * c)) - 1.f;
                    hq[q] = ov[q] * th;
                }
#pragma unroll
                for (int q = 0; q < 4; q++)
                    htmp[t & 1][rr0 + q][4 * w + jj] = f2bf(-hq[q]);
                if (t == 1023) {
#pragma unroll
                    for (int q = 0; q < 4; q++) {
                        size_t b = (size_t)g * 16 + rr0 + q;
                        int j = m * 32 + 4 * w + jj;
                        out[BSH + b * 256 + j] = hq[q];
                        out[BSH + BH + b * 256 + j] = cst[q];
                    }
                }
            }
        } else if (w == 8) {
            // 1) issue xp prefetch for step t+6
            if (t + 6 < 1024) {
                int slot = (t + 6) & 7;
                const char* src = (const char*)xp + ((wgx * 1024 + (size_t)(t + 6)) << 12)
                                  + (size_t)lane * 16;
                char* dst = (char*)&xpring[slot][0];
#pragma unroll
                for (int c2 = 0; c2 < 4; c2++)
                    gload_lds16(src + c2 * 1024, dst + c2 * 1024);
            }
            // 2) hidden_seq stores for step t-1
            if (t > 0) {
                int r = lane >> 2, seg = lane & 3;
                uint4_ hv = *(const uint4_*)&htmp[(t - 1) & 1][r][seg * 8];
                hv.x ^= 0x80008000u; hv.y ^= 0x80008000u;
                hv.z ^= 0x80008000u; hv.w ^= 0x80008000u;   // -(-h) = h
                float4_ v0 = { bf2f((unsigned short)(hv.x & 0xffff)), bf2f((unsigned short)(hv.x >> 16)),
                               bf2f((unsigned short)(hv.y & 0xffff)), bf2f((unsigned short)(hv.y >> 16)) };
                float4_ v1 = { bf2f((unsigned short)(hv.z & 0xffff)), bf2f((unsigned short)(hv.z >> 16)),
                               bf2f((unsigned short)(hv.w & 0xffff)), bf2f((unsigned short)(hv.w >> 16)) };
                float* po = out + (((size_t)(g * 16 + r)) << 18) + ((size_t)(t - 1) << 8)
                            + m * 32 + seg * 8;
                *(float4_*)po = v0;
                *(float4_*)(po + 4) = v1;
            }
            // 3) guarantee slot t+1 is resident before the barrier (counted!)
            if (t == 0)            asm volatile("s_waitcnt vmcnt(20)" ::: "memory");
            else if (t == 1)       asm volatile("s_waitcnt vmcnt(22)" ::: "memory");
            else if (t + 6 < 1024) asm volatile("s_waitcnt vmcnt(24)" ::: "memory");
            else                   asm volatile("s_waitcnt vmcnt(0)"  ::: "memory");
        }
        barrier_lgkm();
        if (w == m) {   // publish -h(t): fire-and-forget, data-is-the-flag
            int rr = lane & 15, kg = lane >> 4;
            uint4_ hv = *(const uint4_*)&htmp[t & 1][rr][kg * 8];
            const char* hd = (const char*)hbuf + (((size_t)t * 4 + g) << 13)
                             + m * 1024 + (size_t)lane * 16;
            asm volatile("s_waitcnt lgkmcnt(0)" ::: "memory");
            asm volatile("global_store_dwordx4 %0, %1, off sc0 sc1"
                         :: "v"(hd), "v"(hv) : "memory");
        }
    }
    // epilogue: hidden_seq for t=1023
    if (w == 8) {
        int r = lane >> 2, seg = lane & 3;
        uint4_ hv = *(const uint4_*)&htmp[1][r][seg * 8];
        hv.x ^= 0x80008000u; hv.y ^= 0x80008000u;
        hv.z ^= 0x80008000u; hv.w ^= 0x80008000u;
        float4_ v0 = { bf2f((unsigned short)(hv.x & 0xffff)), bf2f((unsigned short)(hv.x >> 16)),
                       bf2f((unsigned short)(hv.y & 0xffff)), bf2f((unsigned short)(hv.y >> 16)) };
        float4_ v1 = { bf2f((unsigned short)(hv.z & 0xffff)), bf2f((unsigned short)(hv.z >> 16)),
                       bf2f((unsigned short)(hv.w & 0xffff)), bf2f((unsigned short)(hv.w >> 16)) };
        float* po = out + (((size_t)(g * 16 + r)) << 18) + ((size_t)1023 << 8) + m * 32 + seg * 8;
        *(float4_*)po = v0;
        *(float4_*)(po + 4) = v1;
    }
}

__global__ void ws_too_small_kernel(float* out) {
    if (threadIdx.x == 0 && blockIdx.x == 0) out[0] = -777777.0f;
}

extern "C" void kernel_launch(void* const* d_in, const int* in_sizes, int n_in,
                              void* d_out, int out_size, void* d_ws, size_t ws_size,
                              hipStream_t stream) {
    const float* x    = (const float*)d_in[0];
    const float* lam  = (const float*)d_in[1];
    const float* W    = (const float*)d_in[2];
    const float* U    = (const float*)d_in[3];
    const float* bias = (const float*)d_in[4];
    float* out = (float*)d_out;

    const size_t NEED = (size_t)162 << 20;   // 2MiB prep + 32MiB hbuf + 128MiB xp
    if (ws_size < NEED) {
        ws_too_small_kernel<<<1, 64, 0, stream>>>(out);
        return;
    }
    char* ws = (char*)d_ws;
    unsigned short* Ubf   = (unsigned short*)(ws + (256 << 10));       // 512KB
    unsigned short* Wbf   = (unsigned short*)(ws + (768 << 10));       // 512KB
    float*          biasf = (float*)(ws + (1280 << 10));               // 4KB
    unsigned short* hbuf  = (unsigned short*)(ws + ((size_t)2 << 20)); // 32MiB
    unsigned short* xp    = (unsigned short*)(ws + ((size_t)34 << 20));// 128MiB

    hipMemsetAsync(hbuf, 0, (size_t)32 << 20, stream);   // sentinel for data-poll
    prep_kernel<<<260, 256, 0, stream>>>(W, U, bias, Wbf, Ubf, biasf);
    xproj_kernel<<<1024, 512, 0, stream>>>(x, Wbf, biasf, xp);
    lstm_kernel<<<32, 576, 0, stream>>>(Ubf, xp, lam, hbuf, out);
}